// Round 3
// baseline (217.303 us; speedup 1.0000x reference)
//
#include <hip/hip_runtime.h>

#define HH 256
#define NPIX (HH * HH)
#define TOPK 200
#define MIN_COUNT 400
#define FOCAL 221.0f
#define NT 1024               // threads per block
#define NW (NT / 64)          // 16 waves
#define ITERS (NPIX / 4 / NT) // 16 float4 iterations per thread

__device__ __forceinline__ float waveReduceSumF(float v) {
    #pragma unroll
    for (int off = 32; off > 0; off >>= 1)
        v += __shfl_xor(v, off, 64);
    return v;
}

// One block (1024 threads = 16 waves) per batch image; 512 blocks = 2/CU,
// 32 waves/CU. launch_bounds(1024,8) caps VGPR at 64 so both blocks reside.
__global__ __launch_bounds__(NT, 8)
void mask2cube_kernel(const float* __restrict__ x, float* __restrict__ out) {
    const int b    = blockIdx.x;
    const int t    = threadIdx.x;
    const int wave = t >> 6;
    const int lane = t & 63;
    const float* __restrict__ xb = x + (size_t)b * NPIX;

    __shared__ float colPartW[NW][HH];  // per-wave column weight partials (16 KB)
    __shared__ int   colPartC[NW][HH];  // per-wave column count partials  (16 KB)
    __shared__ float rowW[HH];
    __shared__ int   rowC[HH];
    __shared__ float rowWC[HH];
    __shared__ float colW[HH];
    __shared__ int   colC[HH];
    __shared__ float colWC[HH];
    __shared__ float bN[4], bD[4];
    __shared__ int   bCoord[4], bR[4];
    __shared__ float partF[NW];
    __shared__ int   partI[NW];

    // ---------- Phase 1: stream image, build histograms ----------
    // float4 index f = i*1024 + t  ->  row = 16*i + wave, col = 4*lane + j
    float cW0 = 0.f, cW1 = 0.f, cW2 = 0.f, cW3 = 0.f;
    int   cC0 = 0,   cC1 = 0,   cC2 = 0,   cC3 = 0;
    const float4* __restrict__ xv = (const float4*)xb;

    #pragma unroll
    for (int mac = 0; mac < ITERS / 4; ++mac) {
        float4 v[4];
        #pragma unroll
        for (int u = 0; u < 4; ++u)
            v[u] = xv[(mac * 4 + u) * NT + t];   // 4 loads in flight
        #pragma unroll
        for (int u = 0; u < 4; ++u) {
            const int i = mac * 4 + u;
            bool m0 = v[u].x > 0.5f, m1 = v[u].y > 0.5f;
            bool m2 = v[u].z > 0.5f, m3 = v[u].w > 0.5f;
            float w0 = m0 ? v[u].x : 0.f, w1 = m1 ? v[u].y : 0.f;
            float w2 = m2 ? v[u].z : 0.f, w3 = m3 ? v[u].w : 0.f;
            cW0 += w0; cW1 += w1; cW2 += w2; cW3 += w3;
            cC0 += m0; cC1 += m1; cC2 += m2; cC3 += m3;
            // this wave covers exactly row 16*i + wave
            float sr = waveReduceSumF((w0 + w1) + (w2 + w3));
            int cnt = __popcll(__ballot(m0)) + __popcll(__ballot(m1))
                    + __popcll(__ballot(m2)) + __popcll(__ballot(m3));
            if (lane == 0) {
                const int row = 16 * i + wave;
                rowW[row] = sr;
                rowC[row] = cnt;
            }
        }
    }

    // write column partials (col = 4*lane+j, one partial set per wave)
    {
        ((float4*)&colPartW[wave][4 * lane])[0] = make_float4(cW0, cW1, cW2, cW3);
        ((int4*)&colPartC[wave][4 * lane])[0]   = make_int4(cC0, cC1, cC2, cC3);
    }
    __syncthreads();

    // combine partials; thread t (<256) owns column t / row t
    if (t < HH) {
        float w = 0.f; int c = 0;
        #pragma unroll
        for (int wv = 0; wv < NW; ++wv) { w += colPartW[wv][t]; c += colPartC[wv][t]; }
        colW[t]  = w;
        colC[t]  = c;
        colWC[t] = w * (float)t;
        rowWC[t] = rowW[t] * (float)t;
    }
    __syncthreads();

    // ---------- Phase 2: inclusive prefix scans over the 256 bins ----------
    #pragma unroll 1
    for (int s = 1; s < HH; s <<= 1) {
        int   cc = 0, rc = 0;
        float cw = 0.f, cwc = 0.f, rw = 0.f, rwc = 0.f;
        const bool act = (t < HH) && (t >= s);
        if (act) {
            cc  = colC[t - s];  cw  = colW[t - s];  cwc = colWC[t - s];
            rc  = rowC[t - s];  rw  = rowW[t - s];  rwc = rowWC[t - s];
        }
        __syncthreads();
        if (act) {
            colC[t] += cc;  colW[t] += cw;  colWC[t] += cwc;
            rowC[t] += rc;  rowW[t] += rw;  rowWC[t] += rwc;
        }
        __syncthreads();
    }

    const int   totalC = colC[HH - 1];
    const float totW   = colW[HH - 1];
    const float totWC  = colWC[HH - 1];
    const float totWCr = rowWC[HH - 1];

    if (totalC <= MIN_COUNT) {   // invalid image -> zeros (uniform branch)
        if (t < 7) out[b * 7 + t] = 0.f;
        return;
    }

    // ---------- Phase 3: boundary detection ----------
    if (t < HH) {
        int   Pc   = colC[t];
        int   Pcm1 = t ? colC[t - 1] : 0;
        float wP   = colW[t],  wcP   = colWC[t];
        float wPm1 = t ? colW[t - 1]  : 0.f;
        float wcPm1= t ? colWC[t - 1] : 0.f;
        if (Pcm1 < TOPK && Pc >= TOPK) {                      // x_min (k=1)
            bCoord[1] = t; bR[1] = TOPK - Pcm1; bN[1] = wcPm1; bD[1] = wPm1;
        }
        if ((totalC - Pc) < TOPK && (totalC - Pcm1) >= TOPK) { // x_max (k=0)
            bCoord[0] = t; bR[0] = TOPK - (totalC - Pc);
            bN[0] = totWC - wcP; bD[0] = totW - wP;
        }
        int   Rc   = rowC[t];
        int   Rcm1 = t ? rowC[t - 1] : 0;
        float rwP  = rowW[t],  rwcP  = rowWC[t];
        float rwPm1 = t ? rowW[t - 1]  : 0.f;
        float rwcPm1= t ? rowWC[t - 1] : 0.f;
        if (Rcm1 < TOPK && Rc >= TOPK) {                      // y_min (k=3)
            bCoord[3] = t; bR[3] = TOPK - Rcm1; bN[3] = rwcPm1; bD[3] = rwPm1;
        }
        if ((totalC - Rc) < TOPK && (totalC - Rcm1) >= TOPK) { // y_max (k=2)
            bCoord[2] = t; bR[2] = TOPK - (totalC - Rc);
            bN[2] = totWCr - rwcP; bD[2] = totW - rwP;
        }
    }
    __syncthreads();

    // ---------- Phase 4: boundary-line partial sums (exact tie-break) ----------
    float means[4];
    #pragma unroll
    for (int k = 0; k < 4; ++k) {
        const int cs = bCoord[k];
        const int r  = bR[k];
        float w = 0.f;
        bool  m = false;
        if (t < HH) {
            // k<2: boundary column cs, order = increasing y (= flat index)
            // k>=2: boundary row cs,   order = increasing x (= flat index)
            w = (k < 2) ? xb[(size_t)t * HH + cs] : xb[(size_t)cs * HH + t];
            m = w > 0.5f;
        }
        unsigned long long bal = __ballot(m);
        int lanePfx = __popcll(bal & ((1ull << lane) - 1ull));
        int wTot    = __popcll(bal);
        if (lane == 0) partI[wave] = wTot;
        __syncthreads();
        int wOff = 0;
        #pragma unroll
        for (int ww = 0; ww < NW; ++ww)
            if (ww < wave) wOff += partI[ww];
        int pfx = wOff + lanePfx;
        float sel = (m && (pfx < r)) ? w : 0.f;
        float sr = waveReduceSumF(sel);
        if (lane == 0) partF[wave] = sr;
        __syncthreads();
        float part = 0.f;
        #pragma unroll
        for (int ww = 0; ww < NW; ++ww) part += partF[ww];
        means[k] = (bN[k] + part * (float)cs) / (bD[k] + part);
        __syncthreads();
    }

    // ---------- Phase 5: final 7-vector ----------
    if (t == 0) {
        float x_maxw = means[0], x_minw = means[1];
        float y_maxw = means[2], y_minw = means[3];
        float y_min = 255.0f - y_maxw;
        float y_max = 255.0f - y_minw;
        float z = 1.0f + y_min / 128.0f;
        float xm = x_minw - 128.0f;
        float xM = x_maxw - 128.0f;
        float x3min = xm / FOCAL / z;
        float x3max = xM / FOCAL / z;
        float y3min = y_min / FOCAL / z;
        float y3max = y_max / FOCAL / z;
        float* o = out + b * 7;
        o[0] = (x3max + x3min) * 0.5f;
        o[1] = (y3max + y3min) * 0.5f;
        o[2] = z;
        o[3] = (x3max - x3min) * 0.5f;
        o[4] = (y3max - y3min) * 0.5f;
        o[5] = 0.1f;
        o[6] = 0.0f;
    }
}

extern "C" void kernel_launch(void* const* d_in, const int* in_sizes, int n_in,
                              void* d_out, int out_size, void* d_ws, size_t ws_size,
                              hipStream_t stream) {
    const float* x = (const float*)d_in[0];
    float* out = (float*)d_out;
    const int B = in_sizes[0] / NPIX;
    mask2cube_kernel<<<B, NT, 0, stream>>>(x, out);
}

// Round 4
// 200.824 us; speedup vs baseline: 1.0821x; 1.0821x over previous
//
#include <hip/hip_runtime.h>

#define HH 256
#define NPIX (HH * HH)
#define TOPK 200
#define MIN_COUNT 400
#define FOCAL 221.0f
#define NT 1024               // threads per block
#define NW (NT / 64)          // 16 waves
#define ITERS (NPIX / 4 / NT) // 16 float4 iterations per thread

__device__ __forceinline__ float waveReduceSumF(float v) {
    #pragma unroll
    for (int off = 32; off > 0; off >>= 1)
        v += __shfl_xor(v, off, 64);
    return v;
}

// One block (1024 threads = 16 waves) per batch image; 512 blocks.
// launch_bounds(1024,4): VGPR budget 128 so NO scratch spill (round-3 lesson:
// (1024,8) forced 32 VGPRs -> 92 MB spill traffic). Actual use ~48-64 VGPRs
// -> HW still co-schedules 2 blocks/CU when <=64.
__global__ __launch_bounds__(NT, 4)
void mask2cube_kernel(const float* __restrict__ x, float* __restrict__ out) {
    const int b    = blockIdx.x;
    const int t    = threadIdx.x;
    const int wave = t >> 6;
    const int lane = t & 63;
    const float* __restrict__ xb = x + (size_t)b * NPIX;

    __shared__ float colPartW[NW][HH];  // per-wave column weight partials (16 KB)
    __shared__ int   colPartC[NW][HH];  // per-wave column count partials  (16 KB)
    __shared__ float rowW[HH];
    __shared__ int   rowC[HH];
    __shared__ float rowWC[HH];
    __shared__ float colW[HH];
    __shared__ int   colC[HH];
    __shared__ float colWC[HH];
    __shared__ float bN[4], bD[4];
    __shared__ int   bCoord[4], bR[4];
    __shared__ float partF[NW];
    __shared__ int   partI[NW];

    // ---------- Phase 1: stream image, build histograms ----------
    // float4 index f = i*1024 + t  ->  row = 16*i + wave, col = 4*lane + j
    float cW0 = 0.f, cW1 = 0.f, cW2 = 0.f, cW3 = 0.f;
    int   cC0 = 0,   cC1 = 0,   cC2 = 0,   cC3 = 0;
    const float4* __restrict__ xv = (const float4*)xb;

    #pragma unroll
    for (int mac = 0; mac < ITERS / 4; ++mac) {
        float4 v0 = xv[(mac * 4 + 0) * NT + t];   // 4 loads in flight
        float4 v1 = xv[(mac * 4 + 1) * NT + t];
        float4 v2 = xv[(mac * 4 + 2) * NT + t];
        float4 v3 = xv[(mac * 4 + 3) * NT + t];
        #pragma unroll
        for (int u = 0; u < 4; ++u) {
            float4 v = (u == 0) ? v0 : (u == 1) ? v1 : (u == 2) ? v2 : v3;
            const int i = mac * 4 + u;
            bool m0 = v.x > 0.5f, m1 = v.y > 0.5f;
            bool m2 = v.z > 0.5f, m3 = v.w > 0.5f;
            float w0 = m0 ? v.x : 0.f, w1 = m1 ? v.y : 0.f;
            float w2 = m2 ? v.z : 0.f, w3 = m3 ? v.w : 0.f;
            cW0 += w0; cW1 += w1; cW2 += w2; cW3 += w3;
            cC0 += m0; cC1 += m1; cC2 += m2; cC3 += m3;
            // this wave covers exactly row 16*i + wave
            float sr = waveReduceSumF((w0 + w1) + (w2 + w3));
            int cnt = __popcll(__ballot(m0)) + __popcll(__ballot(m1))
                    + __popcll(__ballot(m2)) + __popcll(__ballot(m3));
            if (lane == 0) {
                const int row = 16 * i + wave;
                rowW[row] = sr;
                rowC[row] = cnt;
            }
        }
    }

    // write column partials (col = 4*lane+j, one partial set per wave)
    {
        ((float4*)&colPartW[wave][4 * lane])[0] = make_float4(cW0, cW1, cW2, cW3);
        ((int4*)&colPartC[wave][4 * lane])[0]   = make_int4(cC0, cC1, cC2, cC3);
    }
    __syncthreads();

    // combine partials; thread t (<256) owns column t / row t
    if (t < HH) {
        float w = 0.f; int c = 0;
        #pragma unroll
        for (int wv = 0; wv < NW; ++wv) { w += colPartW[wv][t]; c += colPartC[wv][t]; }
        colW[t]  = w;
        colC[t]  = c;
        colWC[t] = w * (float)t;
        rowWC[t] = rowW[t] * (float)t;
    }
    __syncthreads();

    // ---------- Phase 2: inclusive prefix scans over the 256 bins ----------
    #pragma unroll 1
    for (int s = 1; s < HH; s <<= 1) {
        int   cc = 0, rc = 0;
        float cw = 0.f, cwc = 0.f, rw = 0.f, rwc = 0.f;
        const bool act = (t < HH) && (t >= s);
        if (act) {
            cc  = colC[t - s];  cw  = colW[t - s];  cwc = colWC[t - s];
            rc  = rowC[t - s];  rw  = rowW[t - s];  rwc = rowWC[t - s];
        }
        __syncthreads();
        if (act) {
            colC[t] += cc;  colW[t] += cw;  colWC[t] += cwc;
            rowC[t] += rc;  rowW[t] += rw;  rowWC[t] += rwc;
        }
        __syncthreads();
    }

    const int   totalC = colC[HH - 1];
    const float totW   = colW[HH - 1];
    const float totWC  = colWC[HH - 1];
    const float totWCr = rowWC[HH - 1];

    if (totalC <= MIN_COUNT) {   // invalid image -> zeros (uniform branch)
        if (t < 7) out[b * 7 + t] = 0.f;
        return;
    }

    // ---------- Phase 3: boundary detection ----------
    if (t < HH) {
        int   Pc   = colC[t];
        int   Pcm1 = t ? colC[t - 1] : 0;
        float wP   = colW[t],  wcP   = colWC[t];
        float wPm1 = t ? colW[t - 1]  : 0.f;
        float wcPm1= t ? colWC[t - 1] : 0.f;
        if (Pcm1 < TOPK && Pc >= TOPK) {                      // x_min (k=1)
            bCoord[1] = t; bR[1] = TOPK - Pcm1; bN[1] = wcPm1; bD[1] = wPm1;
        }
        if ((totalC - Pc) < TOPK && (totalC - Pcm1) >= TOPK) { // x_max (k=0)
            bCoord[0] = t; bR[0] = TOPK - (totalC - Pc);
            bN[0] = totWC - wcP; bD[0] = totW - wP;
        }
        int   Rc   = rowC[t];
        int   Rcm1 = t ? rowC[t - 1] : 0;
        float rwP  = rowW[t],  rwcP  = rowWC[t];
        float rwPm1 = t ? rowW[t - 1]  : 0.f;
        float rwcPm1= t ? rowWC[t - 1] : 0.f;
        if (Rcm1 < TOPK && Rc >= TOPK) {                      // y_min (k=3)
            bCoord[3] = t; bR[3] = TOPK - Rcm1; bN[3] = rwcPm1; bD[3] = rwPm1;
        }
        if ((totalC - Rc) < TOPK && (totalC - Rcm1) >= TOPK) { // y_max (k=2)
            bCoord[2] = t; bR[2] = TOPK - (totalC - Rc);
            bN[2] = totWCr - rwcP; bD[2] = totW - rwP;
        }
    }
    __syncthreads();

    // ---------- Phase 4: boundary-line partial sums (exact tie-break) ----------
    float means[4];
    #pragma unroll
    for (int k = 0; k < 4; ++k) {
        const int cs = bCoord[k];
        const int r  = bR[k];
        float w = 0.f;
        bool  m = false;
        if (t < HH) {
            // k<2: boundary column cs, order = increasing y (= flat index)
            // k>=2: boundary row cs,   order = increasing x (= flat index)
            w = (k < 2) ? xb[(size_t)t * HH + cs] : xb[(size_t)cs * HH + t];
            m = w > 0.5f;
        }
        unsigned long long bal = __ballot(m);
        int lanePfx = __popcll(bal & ((1ull << lane) - 1ull));
        int wTot    = __popcll(bal);
        if (lane == 0) partI[wave] = wTot;
        __syncthreads();
        int wOff = 0;
        #pragma unroll
        for (int ww = 0; ww < NW; ++ww)
            if (ww < wave) wOff += partI[ww];
        int pfx = wOff + lanePfx;
        float sel = (m && (pfx < r)) ? w : 0.f;
        float sr = waveReduceSumF(sel);
        if (lane == 0) partF[wave] = sr;
        __syncthreads();
        float part = 0.f;
        #pragma unroll
        for (int ww = 0; ww < NW; ++ww) part += partF[ww];
        means[k] = (bN[k] + part * (float)cs) / (bD[k] + part);
        __syncthreads();
    }

    // ---------- Phase 5: final 7-vector ----------
    if (t == 0) {
        float x_maxw = means[0], x_minw = means[1];
        float y_maxw = means[2], y_minw = means[3];
        float y_min = 255.0f - y_maxw;
        float y_max = 255.0f - y_minw;
        float z = 1.0f + y_min / 128.0f;
        float xm = x_minw - 128.0f;
        float xM = x_maxw - 128.0f;
        float x3min = xm / FOCAL / z;
        float x3max = xM / FOCAL / z;
        float y3min = y_min / FOCAL / z;
        float y3max = y_max / FOCAL / z;
        float* o = out + b * 7;
        o[0] = (x3max + x3min) * 0.5f;
        o[1] = (y3max + y3min) * 0.5f;
        o[2] = z;
        o[3] = (x3max - x3min) * 0.5f;
        o[4] = (y3max - y3min) * 0.5f;
        o[5] = 0.1f;
        o[6] = 0.0f;
    }
}

extern "C" void kernel_launch(void* const* d_in, const int* in_sizes, int n_in,
                              void* d_out, int out_size, void* d_ws, size_t ws_size,
                              hipStream_t stream) {
    const float* x = (const float*)d_in[0];
    float* out = (float*)d_out;
    const int B = in_sizes[0] / NPIX;
    mask2cube_kernel<<<B, NT, 0, stream>>>(x, out);
}